// Round 9
// baseline (43.493 us; speedup 1.0000x reference)
//
#include <hip/hip_runtime.h>

#define NT 512
#define R_PB 4   // rows per block

// DB4 decomposition low-pass filter (pywt convention), l0..l7
#define L0 -0.010597401784997278f
#define L1f 0.032883011666982945f
#define L2f 0.030841381835986965f
#define L3f -0.18703481171888114f
#define L4f -0.02798376941698385f
#define L5f 0.6308807679295904f
#define L6f 0.7148465705525415f
#define L7f 0.23037781330885523f

// y_lo[t] = sum_m LOR[m] * X(2t-6+m), LOR[m]=LO[7-m]
// y_hi[t] = sum_m HIR[m] * X(2t-6+m), HIR[m]=LO[m]*(m odd ? -1 : +1)

constexpr int B_ROWS = 4096;
constexpr int LVL1 = 4096, N1 = 2051, N2 = 1029, N3 = 518, N4 = 262;
constexpr size_t OFF_CA4 = 0;
constexpr size_t OFF_CD4 = (size_t)B_ROWS * N4;
constexpr size_t OFF_CD3 = OFF_CD4 + (size_t)B_ROWS * N4;
constexpr size_t OFF_CD2 = OFF_CD3 + (size_t)B_ROWS * N3;
constexpr size_t OFF_CD1 = OFF_CD2 + (size_t)B_ROWS * N2;
constexpr int PSTR = 2052;   // P row stride (pad 2051 so P[1] stays 16B-aligned)

// LDS-only barrier: ds-order without draining outstanding global stores.
__device__ __forceinline__ void lds_barrier() {
    asm volatile("s_waitcnt lgkmcnt(0)" ::: "memory");
    __builtin_amdgcn_s_barrier();
    asm volatile("" ::: "memory");
}

// Clamped (symmetric-reflect) single-output pair; boundary t only.
__device__ __forceinline__ void dwt_one_clamped(const float* __restrict__ src, int L, int t,
                                                float& slo, float& shi) {
    constexpr float LOR[8] = {L7f, L6f, L5f, L4f, L3f, L2f, L1f, L0};
    constexpr float HIR[8] = {L0, -L1f, L2f, -L3f, L4f, -L5f, L6f, -L7f};
    const int idx0 = 2 * t - 6;
    slo = 0.f; shi = 0.f;
#pragma unroll
    for (int m = 0; m < 8; ++m) {
        int q = idx0 + m;
        q = (q < 0) ? (-1 - q) : q;
        q = (q >= L) ? (2 * L - 1 - q) : q;
        const float v = src[q];
        slo = fmaf(LOR[m], v, slo);
        shi = fmaf(HIR[m], v, shi);
    }
}

// Consumer-side DWT level (256 threads, tid in [0,256)), 4 outputs/thread.
template <bool SCALE_A>
__device__ __forceinline__ void dwt_level_c(const float* __restrict__ src, int L,
                                            float* __restrict__ dstA, float wa, float ba,
                                            float* __restrict__ outD, float wd, float bd,
                                            int tid) {
    constexpr float LOR[8] = {L7f, L6f, L5f, L4f, L3f, L2f, L1f, L0};
    constexpr float HIR[8] = {L0, -L1f, L2f, -L3f, L4f, -L5f, L6f, -L7f};
    const int N = (L + 7) >> 1;
    const int Mmax = (L - 8) >> 3;

    const float h0 = wd * HIR[0], h1 = wd * HIR[1], h2 = wd * HIR[2], h3 = wd * HIR[3],
                h4 = wd * HIR[4], h5 = wd * HIR[5], h6 = wd * HIR[6], h7 = wd * HIR[7];
    const float g0 = wa * LOR[0], g1 = wa * LOR[1], g2 = wa * LOR[2], g3 = wa * LOR[3],
                g4 = wa * LOR[4], g5 = wa * LOR[5], g6 = wa * LOR[6], g7 = wa * LOR[7];

    for (int m = 1 + tid; m <= Mmax; m += 256) {
        const float4* p = reinterpret_cast<const float4*>(src) + (2 * m - 2);
        const float4 v0 = p[0], v1 = p[1], v2 = p[2], v3 = p[3];
        const float W[16] = {v0.x, v0.y, v0.z, v0.w, v1.x, v1.y, v1.z, v1.w,
                             v2.x, v2.y, v2.z, v2.w, v3.x, v3.y, v3.z, v3.w};
        float accA[4], accD[4];
#pragma unroll
        for (int o = 0; o < 4; ++o) {
            float sd = bd;
            sd = fmaf(h0, W[2 * o + 2], sd);
            sd = fmaf(h1, W[2 * o + 3], sd);
            sd = fmaf(h2, W[2 * o + 4], sd);
            sd = fmaf(h3, W[2 * o + 5], sd);
            sd = fmaf(h4, W[2 * o + 6], sd);
            sd = fmaf(h5, W[2 * o + 7], sd);
            sd = fmaf(h6, W[2 * o + 8], sd);
            sd = fmaf(h7, W[2 * o + 9], sd);
            accD[o] = sd;
            float sa;
            if (SCALE_A) {
                sa = ba;
                sa = fmaf(g0, W[2 * o + 2], sa);
                sa = fmaf(g1, W[2 * o + 3], sa);
                sa = fmaf(g2, W[2 * o + 4], sa);
                sa = fmaf(g3, W[2 * o + 5], sa);
                sa = fmaf(g4, W[2 * o + 6], sa);
                sa = fmaf(g5, W[2 * o + 7], sa);
                sa = fmaf(g6, W[2 * o + 8], sa);
                sa = fmaf(g7, W[2 * o + 9], sa);
            } else {
                sa = LOR[0] * W[2 * o + 2];
                sa = fmaf(LOR[1], W[2 * o + 3], sa);
                sa = fmaf(LOR[2], W[2 * o + 4], sa);
                sa = fmaf(LOR[3], W[2 * o + 5], sa);
                sa = fmaf(LOR[4], W[2 * o + 6], sa);
                sa = fmaf(LOR[5], W[2 * o + 7], sa);
                sa = fmaf(LOR[6], W[2 * o + 8], sa);
                sa = fmaf(LOR[7], W[2 * o + 9], sa);
            }
            accA[o] = sa;
        }
        const int t0 = 4 * m;
        if (SCALE_A) {
            dstA[t0 + 0] = accA[0]; dstA[t0 + 1] = accA[1];
            dstA[t0 + 2] = accA[2]; dstA[t0 + 3] = accA[3];
        } else {
            float4 qa; qa.x = accA[0]; qa.y = accA[1]; qa.z = accA[2]; qa.w = accA[3];
            *(reinterpret_cast<float4*>(dstA) + m) = qa;
        }
        outD[t0 + 0] = accD[0]; outD[t0 + 1] = accD[1];
        outD[t0 + 2] = accD[2]; outD[t0 + 3] = accD[3];
    }

    const int NS = N - 4 * Mmax;   // specials: t in {0..3} U {4*Mmax+4 .. N-1}
    if (tid < NS) {
        const int t = (tid < 4) ? tid : (4 * Mmax + tid);
        float slo, shi;
        dwt_one_clamped(src, L, t, slo, shi);
        dstA[t] = SCALE_A ? fmaf(wa, slo, ba) : slo;
        outD[t] = fmaf(wd, shi, bd);
    }
}

// Producer: one level-1 interior window (outputs t0=4m..4m+3) from global.
__device__ __forceinline__ void l1_do(const float* __restrict__ xr,
                                      float* __restrict__ Pn,
                                      float* __restrict__ cd1,
                                      int m, float w4, float b4) {
    constexpr float LOR[8] = {L7f, L6f, L5f, L4f, L3f, L2f, L1f, L0};
    constexpr float HIR[8] = {L0, -L1f, L2f, -L3f, L4f, -L5f, L6f, -L7f};
    const float4* p = reinterpret_cast<const float4*>(xr) + (2 * m - 2);
    const float4 v0 = p[0], v1 = p[1], v2 = p[2], v3 = p[3];
    const float W[16] = {v0.x, v0.y, v0.z, v0.w, v1.x, v1.y, v1.z, v1.w,
                         v2.x, v2.y, v2.z, v2.w, v3.x, v3.y, v3.z, v3.w};
    const float h0 = w4 * HIR[0], h1 = w4 * HIR[1], h2 = w4 * HIR[2], h3 = w4 * HIR[3],
                h4 = w4 * HIR[4], h5 = w4 * HIR[5], h6 = w4 * HIR[6], h7 = w4 * HIR[7];
    float accA[4], accD[4];
#pragma unroll
    for (int o = 0; o < 4; ++o) {
        float sd = b4;
        sd = fmaf(h0, W[2 * o + 2], sd);
        sd = fmaf(h1, W[2 * o + 3], sd);
        sd = fmaf(h2, W[2 * o + 4], sd);
        sd = fmaf(h3, W[2 * o + 5], sd);
        sd = fmaf(h4, W[2 * o + 6], sd);
        sd = fmaf(h5, W[2 * o + 7], sd);
        sd = fmaf(h6, W[2 * o + 8], sd);
        sd = fmaf(h7, W[2 * o + 9], sd);
        accD[o] = sd;
        float sa = LOR[0] * W[2 * o + 2];
        sa = fmaf(LOR[1], W[2 * o + 3], sa);
        sa = fmaf(LOR[2], W[2 * o + 4], sa);
        sa = fmaf(LOR[3], W[2 * o + 5], sa);
        sa = fmaf(LOR[4], W[2 * o + 6], sa);
        sa = fmaf(LOR[5], W[2 * o + 7], sa);
        sa = fmaf(LOR[6], W[2 * o + 8], sa);
        sa = fmaf(LOR[7], W[2 * o + 9], sa);
        accA[o] = sa;
    }
    const int t0 = 4 * m;
    float4 qa; qa.x = accA[0]; qa.y = accA[1]; qa.z = accA[2]; qa.w = accA[3];
    *(reinterpret_cast<float4*>(Pn) + m) = qa;
    cd1[t0 + 0] = accD[0]; cd1[t0 + 1] = accD[1];
    cd1[t0 + 2] = accD[2]; cd1[t0 + 3] = accD[3];
}

__device__ __forceinline__ void l1_specials(const float* __restrict__ xr,
                                            float* __restrict__ Pn,
                                            float* __restrict__ cd1,
                                            int tid, float w4, float b4) {
    const int t = (tid < 4) ? tid : (2044 + tid);   // {0,1,2,3, 2048,2049,2050}
    float slo, shi;
    dwt_one_clamped(xr, LVL1, t, slo, shi);
    Pn[t] = slo;
    cd1[t] = fmaf(w4, shi, b4);
}

__global__ __launch_bounds__(NT) void lwt_pc_kernel(const float* __restrict__ x,
                                                    const float* __restrict__ w,
                                                    const float* __restrict__ bias,
                                                    float* __restrict__ out) {
    __shared__ __align__(16) float P[2][PSTR];   // cA1 ping-pong
    __shared__ __align__(16) float Q[1032];      // cA2
    __shared__ __align__(16) float Rb[520];      // cA3
    const int tid = threadIdx.x;
    const int row0 = blockIdx.x * R_PB;

    const float w0 = w[0], w1 = w[1], w2 = w[2], w3 = w[3], w4 = w[4];
    const float b0 = bias[0], b1 = bias[1], b2 = bias[2], b3 = bias[3], b4 = bias[4];

    // ---- Prologue: all 8 waves do L1(row0) -> P[0] ----
    {
        const float* xr = x + (size_t)row0 * LVL1;
        float* cd1 = out + OFF_CD1 + (size_t)row0 * N1;
        const int m = 1 + tid;
        if (m <= 511) l1_do(xr, P[0], cd1, m, w4, b4);
        if (tid < 7) l1_specials(xr, P[0], cd1, tid, w4, b4);
    }
    lds_barrier();

    // ---- Main: producers (waves 0-3) L1(row i); consumers (waves 4-7) L2-4(row i-1) ----
    for (int i = 1; i <= R_PB; ++i) {
        const bool doL1 = (i < R_PB);
        const int rowC = row0 + i - 1;
        float* Pn = P[i & 1];
        float* Pc = P[(i - 1) & 1];
        const float* xr = x + (size_t)(row0 + i) * LVL1;        // deref'd only if doL1
        float* cd1 = out + OFF_CD1 + (size_t)(row0 + i) * N1;   // stored only if doL1

        // seg A: L1 windows 1..128  ||  L2: Pc -> Q, cD2
        if (tid < 256) {
            if (doL1 && tid < 128) l1_do(xr, Pn, cd1, 1 + tid, w4, b4);
        } else {
            dwt_level_c<false>(Pc, N1, Q, 0.f, 0.f,
                               out + OFF_CD2 + (size_t)rowC * N2, w3, b3, tid - 256);
        }
        lds_barrier();

        // seg B: L1 windows 129..320  ||  L3: Q -> Rb, cD3
        if (tid < 256) {
            if (doL1 && tid < 192) l1_do(xr, Pn, cd1, 129 + tid, w4, b4);
        } else {
            dwt_level_c<false>(Q, N2, Rb, 0.f, 0.f,
                               out + OFF_CD3 + (size_t)rowC * N3, w2, b2, tid - 256);
        }
        lds_barrier();

        // seg C: L1 windows 321..511 + specials  ||  L4: Rb -> cA4, cD4
        if (tid < 256) {
            if (doL1) {
                if (tid < 191) l1_do(xr, Pn, cd1, 321 + tid, w4, b4);
                if (tid < 7) l1_specials(xr, Pn, cd1, tid, w4, b4);
            }
        } else {
            dwt_level_c<true>(Rb, N3,
                              out + OFF_CA4 + (size_t)rowC * N4, w0, b0,
                              out + OFF_CD4 + (size_t)rowC * N4, w1, b1, tid - 256);
        }
        lds_barrier();
    }
}

extern "C" void kernel_launch(void* const* d_in, const int* in_sizes, int n_in,
                              void* d_out, int out_size, void* d_ws, size_t ws_size,
                              hipStream_t stream) {
    const float* x = (const float*)d_in[0];
    const float* wp = (const float*)d_in[1];
    const float* bp = (const float*)d_in[2];
    float* out = (float*)d_out;
    lwt_pc_kernel<<<dim3(B_ROWS / R_PB), dim3(NT), 0, stream>>>(x, wp, bp, out);
}

// Round 10
// 28.193 us; speedup vs baseline: 1.5427x; 1.5427x over previous
//
#include <hip/hip_runtime.h>

#define NT 256

// DB4 decomposition low-pass filter (pywt convention), l0..l7
#define L0 -0.010597401784997278f
#define L1f 0.032883011666982945f
#define L2f 0.030841381835986965f
#define L3f -0.18703481171888114f
#define L4f -0.02798376941698385f
#define L5f 0.6308807679295904f
#define L6f 0.7148465705525415f
#define L7f 0.23037781330885523f

// y_lo[t] = sum_m LOR[m] * X(2t-6+m), LOR[m]=LO[7-m]
// y_hi[t] = sum_m HIR[m] * X(2t-6+m), HIR[m]=LO[m]*(m odd ? -1 : +1)

constexpr int B_ROWS = 4096;
constexpr int LVL1 = 4096, N1 = 2051, N2 = 1029, N3 = 518, N4 = 262;
constexpr size_t OFF_CA4 = 0;
constexpr size_t OFF_CD4 = (size_t)B_ROWS * N4;
constexpr size_t OFF_CD3 = OFF_CD4 + (size_t)B_ROWS * N4;
constexpr size_t OFF_CD2 = OFF_CD3 + (size_t)B_ROWS * N3;
constexpr size_t OFF_CD1 = OFF_CD2 + (size_t)B_ROWS * N2;

// LDS-only barrier: orders ds_write -> ds_read without draining global stores.
__device__ __forceinline__ void lds_barrier() {
    asm volatile("s_waitcnt lgkmcnt(0)" ::: "memory");
    __builtin_amdgcn_s_barrier();
    asm volatile("" ::: "memory");
}

// Clamped (symmetric-reflect) single-output pair; boundary t only.
__device__ __forceinline__ void dwt_one_clamped(const float* __restrict__ src, int L, int t,
                                                float& slo, float& shi) {
    constexpr float LOR[8] = {L7f, L6f, L5f, L4f, L3f, L2f, L1f, L0};
    constexpr float HIR[8] = {L0, -L1f, L2f, -L3f, L4f, -L5f, L6f, -L7f};
    const int idx0 = 2 * t - 6;
    slo = 0.f; shi = 0.f;
#pragma unroll
    for (int m = 0; m < 8; ++m) {
        int q = idx0 + m;
        q = (q < 0) ? (-1 - q) : q;
        q = (q >= L) ? (2 * L - 1 - q) : q;
        const float v = src[q];
        slo = fmaf(LOR[m], v, slo);
        shi = fmaf(HIR[m], v, shi);
    }
}

// One DWT level from LDS, 4 outputs per thread (t0 = 4m), float4 LDS I/O.
// #pragma unroll 1 keeps the live window single-buffered (VGPR <= 64 target).
template <bool SCALE_A>
__device__ __forceinline__ void dwt_level_blk(const float* __restrict__ src, int L,
                                              float* __restrict__ dstA, float wa, float ba,
                                              float* __restrict__ outD, float wd, float bd) {
    constexpr float LOR[8] = {L7f, L6f, L5f, L4f, L3f, L2f, L1f, L0};
    constexpr float HIR[8] = {L0, -L1f, L2f, -L3f, L4f, -L5f, L6f, -L7f};
    const int N = (L + 7) >> 1;
    const int Mmax = (L - 8) >> 3;     // loads [8m-8, 8m+8) stay inside [0, L)
    const int tid = threadIdx.x;

    const float h0 = wd * HIR[0], h1 = wd * HIR[1], h2 = wd * HIR[2], h3 = wd * HIR[3],
                h4 = wd * HIR[4], h5 = wd * HIR[5], h6 = wd * HIR[6], h7 = wd * HIR[7];
    const float g0 = wa * LOR[0], g1 = wa * LOR[1], g2 = wa * LOR[2], g3 = wa * LOR[3],
                g4 = wa * LOR[4], g5 = wa * LOR[5], g6 = wa * LOR[6], g7 = wa * LOR[7];

#pragma unroll 1
    for (int m = 1 + tid; m <= Mmax; m += NT) {
        const float4* p = reinterpret_cast<const float4*>(src) + (2 * m - 2);
        const float4 v0 = p[0], v1 = p[1], v2 = p[2], v3 = p[3];
        const float W[16] = {v0.x, v0.y, v0.z, v0.w, v1.x, v1.y, v1.z, v1.w,
                             v2.x, v2.y, v2.z, v2.w, v3.x, v3.y, v3.z, v3.w};
        float accA[4], accD[4];
#pragma unroll
        for (int o = 0; o < 4; ++o) {
            float sd = bd;
            sd = fmaf(h0, W[2 * o + 2], sd);
            sd = fmaf(h1, W[2 * o + 3], sd);
            sd = fmaf(h2, W[2 * o + 4], sd);
            sd = fmaf(h3, W[2 * o + 5], sd);
            sd = fmaf(h4, W[2 * o + 6], sd);
            sd = fmaf(h5, W[2 * o + 7], sd);
            sd = fmaf(h6, W[2 * o + 8], sd);
            sd = fmaf(h7, W[2 * o + 9], sd);
            accD[o] = sd;
            float sa;
            if (SCALE_A) {
                sa = ba;
                sa = fmaf(g0, W[2 * o + 2], sa);
                sa = fmaf(g1, W[2 * o + 3], sa);
                sa = fmaf(g2, W[2 * o + 4], sa);
                sa = fmaf(g3, W[2 * o + 5], sa);
                sa = fmaf(g4, W[2 * o + 6], sa);
                sa = fmaf(g5, W[2 * o + 7], sa);
                sa = fmaf(g6, W[2 * o + 8], sa);
                sa = fmaf(g7, W[2 * o + 9], sa);
            } else {
                sa = LOR[0] * W[2 * o + 2];
                sa = fmaf(LOR[1], W[2 * o + 3], sa);
                sa = fmaf(LOR[2], W[2 * o + 4], sa);
                sa = fmaf(LOR[3], W[2 * o + 5], sa);
                sa = fmaf(LOR[4], W[2 * o + 6], sa);
                sa = fmaf(LOR[5], W[2 * o + 7], sa);
                sa = fmaf(LOR[6], W[2 * o + 8], sa);
                sa = fmaf(LOR[7], W[2 * o + 9], sa);
            }
            accA[o] = sa;
        }
        const int t0 = 4 * m;
        if (SCALE_A) {
            dstA[t0 + 0] = accA[0]; dstA[t0 + 1] = accA[1];
            dstA[t0 + 2] = accA[2]; dstA[t0 + 3] = accA[3];
        } else {
            float4 qa; qa.x = accA[0]; qa.y = accA[1]; qa.z = accA[2]; qa.w = accA[3];
            *(reinterpret_cast<float4*>(dstA) + m) = qa;
        }
        outD[t0 + 0] = accD[0]; outD[t0 + 1] = accD[1];
        outD[t0 + 2] = accD[2]; outD[t0 + 3] = accD[3];
    }

    const int NS = N - 4 * Mmax;   // specials: t in {0..3} U {4*Mmax+4 .. N-1}
    if (tid < NS) {
        const int t = (tid < 4) ? tid : (4 * Mmax + tid);
        float slo, shi;
        dwt_one_clamped(src, L, t, slo, shi);
        dstA[t] = SCALE_A ? fmaf(wa, slo, ba) : slo;
        outD[t] = fmaf(wd, shi, bd);
    }
}

// __launch_bounds__(256, 8): request 8 waves/EU -> compiler caps VGPR at 64,
// doubling resident waves (4-5 -> 8 per SIMD). TLP replaces the unroll ILP.
__global__ __launch_bounds__(NT, 8) void lwt_kernel(const float* __restrict__ x,
                                                    const float* __restrict__ w,
                                                    const float* __restrict__ bias,
                                                    float* __restrict__ out) {
    __shared__ __align__(16) float P[N1];   // cA1, later reused for cA3
    __shared__ __align__(16) float Q[N2];   // cA2
    constexpr float LOR[8] = {L7f, L6f, L5f, L4f, L3f, L2f, L1f, L0};
    constexpr float HIR[8] = {L0, -L1f, L2f, -L3f, L4f, -L5f, L6f, -L7f};
    const int row = blockIdx.x;
    const int tid = threadIdx.x;
    const float* __restrict__ xr = x + (size_t)row * LVL1;

    const float w0 = w[0], w1 = w[1], w2 = w[2], w3 = w[3], w4 = w[4];
    const float b0 = bias[0], b1 = bias[1], b2 = bias[2], b3 = bias[3], b4 = bias[4];

    float* outCD1 = out + OFF_CD1 + (size_t)row * N1;
    const float h0 = w4 * HIR[0], h1 = w4 * HIR[1], h2 = w4 * HIR[2], h3 = w4 * HIR[3],
                h4 = w4 * HIR[4], h5 = w4 * HIR[5], h6 = w4 * HIR[6], h7 = w4 * HIR[7];

    // ---- Level 1 from GLOBAL: t0 = 4m, m = 1..511, window floats [8m-8, 8m+8). ----
#pragma unroll 1
    for (int m = 1 + tid; m <= 511; m += NT) {
        const float4* p = reinterpret_cast<const float4*>(xr) + (2 * m - 2);
        const float4 v0 = p[0], v1 = p[1], v2 = p[2], v3 = p[3];
        const float W[16] = {v0.x, v0.y, v0.z, v0.w, v1.x, v1.y, v1.z, v1.w,
                             v2.x, v2.y, v2.z, v2.w, v3.x, v3.y, v3.z, v3.w};
        float accA[4], accD[4];
#pragma unroll
        for (int o = 0; o < 4; ++o) {
            float sd = b4;
            sd = fmaf(h0, W[2 * o + 2], sd);
            sd = fmaf(h1, W[2 * o + 3], sd);
            sd = fmaf(h2, W[2 * o + 4], sd);
            sd = fmaf(h3, W[2 * o + 5], sd);
            sd = fmaf(h4, W[2 * o + 6], sd);
            sd = fmaf(h5, W[2 * o + 7], sd);
            sd = fmaf(h6, W[2 * o + 8], sd);
            sd = fmaf(h7, W[2 * o + 9], sd);
            accD[o] = sd;
            float sa = LOR[0] * W[2 * o + 2];
            sa = fmaf(LOR[1], W[2 * o + 3], sa);
            sa = fmaf(LOR[2], W[2 * o + 4], sa);
            sa = fmaf(LOR[3], W[2 * o + 5], sa);
            sa = fmaf(LOR[4], W[2 * o + 6], sa);
            sa = fmaf(LOR[5], W[2 * o + 7], sa);
            sa = fmaf(LOR[6], W[2 * o + 8], sa);
            sa = fmaf(LOR[7], W[2 * o + 9], sa);
            accA[o] = sa;
        }
        const int t0 = 4 * m;
        float4 qa; qa.x = accA[0]; qa.y = accA[1]; qa.z = accA[2]; qa.w = accA[3];
        *(reinterpret_cast<float4*>(P) + m) = qa;
        outCD1[t0 + 0] = accD[0]; outCD1[t0 + 1] = accD[1];
        outCD1[t0 + 2] = accD[2]; outCD1[t0 + 3] = accD[3];
    }
    if (tid < 7) {   // t in {0,1,2,3, 2048, 2049, 2050}
        const int t = (tid < 4) ? tid : (2044 + tid);
        float slo, shi;
        dwt_one_clamped(xr, LVL1, t, slo, shi);
        P[t] = slo;
        outCD1[t] = fmaf(w4, shi, b4);
    }

    lds_barrier();
    dwt_level_blk<false>(P, N1, Q, 0.f, 0.f, out + OFF_CD2 + (size_t)row * N2, w3, b3);
    lds_barrier();
    dwt_level_blk<false>(Q, N2, P, 0.f, 0.f, out + OFF_CD3 + (size_t)row * N3, w2, b2);
    lds_barrier();
    dwt_level_blk<true>(P, N3, out + OFF_CA4 + (size_t)row * N4, w0, b0,
                        out + OFF_CD4 + (size_t)row * N4, w1, b1);
}

extern "C" void kernel_launch(void* const* d_in, const int* in_sizes, int n_in,
                              void* d_out, int out_size, void* d_ws, size_t ws_size,
                              hipStream_t stream) {
    const float* x = (const float*)d_in[0];
    const float* wp = (const float*)d_in[1];
    const float* bp = (const float*)d_in[2];
    float* out = (float*)d_out;
    lwt_kernel<<<dim3(B_ROWS), dim3(NT), 0, stream>>>(x, wp, bp, out);
}